// Round 11
// baseline (135145.862 us; speedup 1.0000x reference)
//
#include <hip/hip_runtime.h>
#include <stdint.h>

typedef short s16x8 __attribute__((ext_vector_type(8)));
typedef float f32x4 __attribute__((ext_vector_type(4)));
typedef int   i32x4 __attribute__((ext_vector_type(4)));

#define DEV static __device__ __forceinline__

DEV float bf2f(ushort u){ union{uint i;float f;}v; v.i=((uint)u)<<16; return v.f; }
DEV ushort f2bf(float f){ union{float f;uint i;}v; v.f=f; return (ushort)((v.i + 0x7FFFu + ((v.i>>16)&1u))>>16); }
DEV float fsigmoid(float x){ return 1.f/(1.f+__expf(-x)); }
DEV float fgelu(float x){
  float u = 0.7978845608028654f*(x + 0.044715f*x*x*x);
  float e = __expf(2.f*u);
  float th = 1.f - 2.f/(e+1.f);   // tanh(u), stable
  return 0.5f*x*(1.f+th);
}
DEV f32x4 mfma16(s16x8 a, s16x8 b, f32x4 c){
  return __builtin_amdgcn_mfma_f32_16x16x32_bf16(a,b,c,0,0,0);
}

// ---------------- transpose + f32->bf16 convert: dst[N][K] = bf16(src[K][N]) ----------------
__global__ __launch_bounds__(256) void transpose_cvt(const float* __restrict__ src,
                                                     ushort* __restrict__ dst, int K, int N){
  __shared__ float tile[64][65];
  int tk = blockIdx.y*64, tn = blockIdx.x*64;
  int t = threadIdx.x;
  int c4 = (t & 15)*4, r0 = t >> 4;
  #pragma unroll
  for (int p=0;p<4;++p){
    int r = r0 + p*16;
    float4 v = *(const float4*)(src + (size_t)(tk+r)*N + tn + c4);
    tile[r][c4+0]=v.x; tile[r][c4+1]=v.y; tile[r][c4+2]=v.z; tile[r][c4+3]=v.w;
  }
  __syncthreads();
  #pragma unroll
  for (int p=0;p<4;++p){
    int n = r0 + p*16;
    ushort4 o = make_ushort4(f2bf(tile[c4+0][n]), f2bf(tile[c4+1][n]),
                             f2bf(tile[c4+2][n]), f2bf(tile[c4+3][n]));
    *(ushort4*)(dst + (size_t)(tn+n)*K + tk + c4) = o;
  }
}

// ---------------- elementwise f32->bf16 ----------------
__global__ __launch_bounds__(256) void cvt_bf16(const float* __restrict__ s,
                                                ushort* __restrict__ d, int n){
  int i = (blockIdx.x*256 + threadIdx.x)*4;
  if (i < n){
    float4 v = *(const float4*)(s + i);
    ushort4 o = make_ushort4(f2bf(v.x), f2bf(v.y), f2bf(v.z), f2bf(v.w));
    *(ushort4*)(d + i) = o;
  }
}

__global__ __launch_bounds__(256) void bias_sum_k(const float* __restrict__ a,
                                                  const float* __restrict__ b,
                                                  float* __restrict__ o){
  int i = blockIdx.x*256 + threadIdx.x;
  if (i < 1024) o[i] = a[i] + b[i];
}

// fused bias: o[n] = sum_k b_in[k]*W[k][n] + b_out[n]
__global__ __launch_bounds__(256) void fuse_bias(const float* __restrict__ b_in,
                                                 const float* __restrict__ W,
                                                 const float* __restrict__ b_out,
                                                 float* __restrict__ o, int K, int N){
  int n = blockIdx.x*256 + threadIdx.x;
  if (n < N){
    float s = b_out[n];
    for (int k=0;k<K;++k) s += b_in[k]*W[(size_t)k*N + n];
    o[n] = s;
  }
}

// ---------------- RMSNorm: f32 in -> bf16 out (does not modify input) ----------------
__global__ __launch_bounds__(256) void rms_kernel(const float* __restrict__ x,
                                                  const float* __restrict__ scale,
                                                  ushort* __restrict__ out){
  int row = blockIdx.x, t = threadIdx.x;
  const float* xr = x + (size_t)row*1024;
  float4 v = *(const float4*)(xr + t*4);
  float ss = v.x*v.x + v.y*v.y + v.z*v.z + v.w*v.w;
  #pragma unroll
  for (int o=1;o<64;o<<=1) ss += __shfl_xor(ss, o);
  __shared__ float wsum[4];
  if ((t & 63)==0) wsum[t>>6] = ss;
  __syncthreads();
  float tot = wsum[0]+wsum[1]+wsum[2]+wsum[3];
  float rstd = rsqrtf(tot*(1.f/1024.f) + 1e-6f);
  float4 sc = *(const float4*)(scale + t*4);
  ushort4 o4 = make_ushort4(f2bf(v.x*sc.x*rstd), f2bf(v.y*sc.y*rstd),
                            f2bf(v.z*sc.z*rstd), f2bf(v.w*sc.w*rstd));
  *(ushort4*)(out + (size_t)row*1024 + t*4) = o4;
}

// ---------------- x_res = xr + h_seq (in-place), then RMSNorm2 -> xn2(bf16) --------------
__global__ __launch_bounds__(256) void addrms2_kernel(float* __restrict__ xr,
                                                      const ushort* __restrict__ hs,
                                                      const float* __restrict__ scale,
                                                      ushort* __restrict__ out){
  int row = blockIdx.x, t = threadIdx.x;
  float* p = xr + (size_t)row*1024 + t*4;
  float4 v = *(const float4*)p;
  ushort4 hh = *(const ushort4*)(hs + (size_t)row*1024 + t*4);
  v.x += bf2f(hh.x); v.y += bf2f(hh.y); v.z += bf2f(hh.z); v.w += bf2f(hh.w);
  *(float4*)p = v;
  float ss = v.x*v.x + v.y*v.y + v.z*v.z + v.w*v.w;
  #pragma unroll
  for (int o=1;o<64;o<<=1) ss += __shfl_xor(ss, o);
  __shared__ float wsum[4];
  if ((t & 63)==0) wsum[t>>6] = ss;
  __syncthreads();
  float tot = wsum[0]+wsum[1]+wsum[2]+wsum[3];
  float rstd = rsqrtf(tot*(1.f/1024.f) + 1e-6f);
  float4 sc = *(const float4*)(scale + t*4);
  ushort4 o4 = make_ushort4(f2bf(v.x*sc.x*rstd), f2bf(v.y*sc.y*rstd),
                            f2bf(v.z*sc.z*rstd), f2bf(v.w*sc.w*rstd));
  *(ushort4*)(out + (size_t)row*1024 + t*4) = o4;
}

// ---------------- W quantization: WqT[c][k] = i8(W[k][c]/s), sW[c] = colmax/127 ----------
__global__ __launch_bounds__(256) void quant_w(const float* __restrict__ W,
                                               char* __restrict__ WqT,
                                               float* __restrict__ sW){
  __shared__ float red[16][16];
  const int t = threadIdx.x;
  const int c  = blockIdx.x*16 + (t & 15);
  const int kl = t >> 4;
  float m = 0.f;
  for (int n=0;n<64;++n){
    float w = W[(size_t)(kl*64+n)*1024 + c];
    m = fmaxf(m, fabsf(w));
  }
  red[kl][t & 15] = m;
  __syncthreads();
  float cm = 1e-20f;
  #pragma unroll
  for (int i=0;i<16;++i) cm = fmaxf(cm, red[i][t & 15]);
  if (kl == 0) sW[c] = cm*(1.f/127.f);
  float inv = 127.f/cm;
  for (int n=0;n<64;n+=4){
    uint pk = 0;
    #pragma unroll
    for (int d=0;d<4;++d){
      float w = W[(size_t)(kl*64+n+d)*1024 + c];
      int q = __float2int_rn(w*inv);
      pk |= ((uint)(uchar)(char)q) << (8*d);
    }
    *(uint*)(WqT + (size_t)c*1024 + kl*64 + n) = pk;
  }
}

// ---------------- GEMM: C = epi(A[M][K](bf16) @ Bt[N][K](bf16)^T + bias) ----------------
// EPI: 0 bf16  1 gelu->bf16  2 sigmoid->bf16  3 clip(sigmoid*aux0)->bf16
//      4 f32 = v + aux0_f32 + 0.1*aux1_bf16   5 f32 +=   6 bf16 scattered vhT
//      7 bf16 transposed store [col*M+row]
template<int EPI>
__global__ __launch_bounds__(256,2) void gemm_bf16(
    const ushort* __restrict__ A, const ushort* __restrict__ Bt,
    const float* __restrict__ bias, void* __restrict__ Cout,
    const void* __restrict__ aux0, const void* __restrict__ aux1,
    int M, int N, int K)
{
  __shared__ ushort Al[128*32];
  __shared__ ushort Bl[128*32];
  const int t = threadIdx.x, ln = t & 63;
  const int m0 = blockIdx.y*128, n0 = blockIdx.x*128;
  const int wv = t >> 6, wr = wv >> 1, wc = wv & 1;
  const int lr = ln & 15, lk = ln >> 4;
  f32x4 acc[4][4] = {};
  for (int kk = 0; kk < K; kk += 32) {
    #pragma unroll
    for (int cc = 0; cc < 2; ++cc) {
      int e = cc*256 + t;
      int r = e >> 2, sg = e & 3;
      s16x8 va = *(const s16x8*)(A  + (size_t)(m0+r)*K + kk + sg*8);
      s16x8 vb = *(const s16x8*)(Bt + (size_t)(n0+r)*K + kk + sg*8);
      *(s16x8*)&Al[e*8] = va;
      *(s16x8*)&Bl[e*8] = vb;
    }
    __syncthreads();
    s16x8 af[4], bfr[4];
    #pragma unroll
    for (int m=0;m<4;++m) af[m]  = *(const s16x8*)&Al[(wr*64 + m*16 + lr)*32 + lk*8];
    #pragma unroll
    for (int n=0;n<4;++n) bfr[n] = *(const s16x8*)&Bl[(wc*64 + n*16 + lr)*32 + lk*8];
    #pragma unroll
    for (int m=0;m<4;++m)
      #pragma unroll
      for (int n=0;n<4;++n)
        acc[m][n] = mfma16(af[m], bfr[n], acc[m][n]);
    __syncthreads();
  }
  #pragma unroll
  for (int m=0;m<4;++m){
    #pragma unroll
    for (int n=0;n<4;++n){
      #pragma unroll
      for (int j=0;j<4;++j){
        int row = m0 + wr*64 + m*16 + lk*4 + j;
        int col = n0 + wc*64 + n*16 + lr;
        float v = acc[m][n][j] + (bias ? bias[col] : 0.f);
        size_t idx = (size_t)row*N + col;
        if constexpr (EPI==0){ ((ushort*)Cout)[idx] = f2bf(v); }
        else if constexpr (EPI==1){ ((ushort*)Cout)[idx] = f2bf(fgelu(v)); }
        else if constexpr (EPI==2){ ((ushort*)Cout)[idx] = f2bf(fsigmoid(v)); }
        else if constexpr (EPI==3){
          float g = fsigmoid(v) * bf2f(((const ushort*)aux0)[idx]);
          g = fminf(fmaxf(g, 1e-6f), 1.f-1e-6f);
          ((ushort*)Cout)[idx] = f2bf(g);
        }
        else if constexpr (EPI==4){
          float o = v + ((const float*)aux0)[idx] + 0.1f*bf2f(((const ushort*)aux1)[idx]);
          ((float*)Cout)[idx] = o;
        }
        else if constexpr (EPI==5){ ((float*)Cout)[idx] += v; }
        else if constexpr (EPI==6){
          int bb = row >> 9, mm = row & 511, hh = col >> 7, dd = col & 127;
          ((ushort*)Cout)[ (((size_t)(bb*8 + hh)*128 + dd) << 9) + mm ] = f2bf(v);
        }
        else if constexpr (EPI==7){
          ((ushort*)Cout)[(size_t)col*M + row] = f2bf(v);
        }
      }
    }
  }
}

// ---------------- memory attention: per (b,h,s-tile 64), M=512, hd=128 -------------------
__global__ __launch_bounds__(256,1) void attn_kernel(
  const ushort* __restrict__ qh, const ushort* __restrict__ kh,
  const ushort* __restrict__ vhT, ushort* __restrict__ att)
{
  __shared__ ushort P[4*16*512];   // 64KB, per-wave 16x512 bf16, XOR-swizzled
  const int t = threadIdx.x, ln = t & 63, wv = t >> 6;
  const int lr = ln & 15, lk = ln >> 4;
  const int b = blockIdx.z, h = blockIdx.y, s0 = blockIdx.x*64;

  const ushort* qrow = qh + (size_t)(b*4096 + s0 + wv*16 + lr)*1024 + h*128 + lk*8;
  s16x8 qf[4];
  #pragma unroll
  for (int kt=0;kt<4;++kt) qf[kt] = *(const s16x8*)(qrow + kt*32);
  __syncthreads();   // all q reads complete before any in-place writes later

  f32x4 zero4 = {0.f,0.f,0.f,0.f};
  f32x4 sacc[32];
  #pragma unroll
  for (int i=0;i<32;++i) sacc[i] = zero4;

  const ushort* kbase = kh + (size_t)(b*512)*1024 + h*128 + lk*8;
  #pragma unroll
  for (int mt=0;mt<32;++mt){
    const ushort* krow = kbase + (size_t)(mt*16 + lr)*1024;
    #pragma unroll
    for (int kt=0;kt<4;++kt){
      s16x8 kf = *(const s16x8*)(krow + kt*32);
      sacc[mt] = mfma16(qf[kt], kf, sacc[mt]);
    }
  }
  const float scale = 0.08838834764831845f;  // 1/sqrt(128)
  float inv[4];
  #pragma unroll
  for (int j=0;j<4;++j){
    float m = -3.4e38f;
    #pragma unroll
    for (int mt=0;mt<32;++mt) m = fmaxf(m, sacc[mt][j]);
    m = fmaxf(m, __shfl_xor(m,1)); m = fmaxf(m, __shfl_xor(m,2));
    m = fmaxf(m, __shfl_xor(m,4)); m = fmaxf(m, __shfl_xor(m,8));
    float s = 0.f;
    #pragma unroll
    for (int mt=0;mt<32;++mt){
      float p = __expf((sacc[mt][j]-m)*scale);
      sacc[mt][j] = p; s += p;
    }
    s += __shfl_xor(s,1); s += __shfl_xor(s,2);
    s += __shfl_xor(s,4); s += __shfl_xor(s,8);
    inv[j] = 1.f/s;
  }
  char* pb = (char*)P + wv*16384;
  #pragma unroll
  for (int j=0;j<4;++j){
    int row = lk*4 + j;
    uint xr = (uint)((row & 7) << 4);
    #pragma unroll
    for (int mt=0;mt<32;++mt){
      int col = mt*16 + lr;
      *(ushort*)(pb + row*1024 + (((uint)(col*2)) ^ xr)) = f2bf(sacc[mt][j]);
    }
  }
  f32x4 oacc[8];
  #pragma unroll
  for (int i=0;i<8;++i) oacc[i] = zero4;
  const ushort* vb = vhT + (size_t)(b*8 + h)*128*512;
  const char* prow = (char*)P + wv*16384 + lr*1024;
  uint xrr = (uint)((lr & 7) << 4);
  #pragma unroll
  for (int km=0;km<16;++km){
    s16x8 pf = *(const s16x8*)(prow + (((uint)((km*32 + lk*8)*2)) ^ xrr));
    #pragma unroll
    for (int dt=0;dt<8;++dt){
      s16x8 vf = *(const s16x8*)(vb + (size_t)(dt*16 + lr)*512 + km*32 + lk*8);
      oacc[dt] = mfma16(pf, vf, oacc[dt]);
    }
  }
  ushort* ob = att + (size_t)(b*4096 + s0 + wv*16)*1024 + h*128;
  #pragma unroll
  for (int dt=0;dt<8;++dt){
    #pragma unroll
    for (int j=0;j<4;++j){
      int row = lk*4 + j, col = dt*16 + lr;
      ob[(size_t)row*1024 + col] = f2bf(oacc[dt][j]*inv[j]);
    }
  }
}

// ---------------- sequential gated scan: SINGLE CU, W int8-resident in registers ---------
// 1 block x 1024 threads (16 waves). Wq (i8, 1MB) lives in VGPRs: 128 i64 fragments/lane.
// Per step: 2048 x mfma_i32_16x16x32_i8 + 2 intra-block barriers (no cross-block sync!).
// h stays f32 in registers; matvec input quantized i8 with per-step per-batch scale.
__global__ __launch_bounds__(1024,1) void scan_kernel(
  const char* __restrict__ Wq,     // [1024 c][1024 k] i8
  const float* __restrict__ sW,    // [1024] per-col scale
  const ushort* __restrict__ u_bf, const ushort* __restrict__ z_bf,
  const ushort* __restrict__ g_bf, ushort* __restrict__ h_seq)
{
  __shared__ signed char HQ[2][16][1032];  // rows 0-3 = batches, 4-15 = zeros; pad->2-way
  __shared__ float smax[16][4];
  const int t = threadIdx.x, w = t >> 6, ln = t & 63;
  for (int e = t; e < 2*16*1032; e += 1024) ((signed char*)HQ)[e] = 0;

  // ---- W fragments into registers: frag f=(kt*4+ct): B[k][c], c=w*64+ct*16+(ln&15) ----
  long long wfrag[128];
  {
    const char* wqb = Wq + (size_t)(w*64 + (ln & 15))*1024 + (ln >> 4)*8;
    #pragma unroll
    for (int f = 0; f < 128; ++f) {
      int kt = f >> 2, ct = f & 3;
      wfrag[f] = *(const long long*)(wqb + (size_t)ct*16384 + kt*32);
    }
  }
  const bool epi = (ln < 16);
  const int colb = w*64 + ln;            // epilogue col for ct: colb + ct*16
  float hst[4][4] = {};
  float uu[4][4], zz[4][4], gg[4][4], sWr[4];
  float shc[4] = {1.f, 1.f, 1.f, 1.f};
  if (epi) {
    #pragma unroll
    for (int ct = 0; ct < 4; ++ct) {
      sWr[ct] = sW[colb + ct*16];
      #pragma unroll
      for (int j = 0; j < 4; ++j) {
        size_t idx = ((size_t)(j*4096))*1024 + colb + ct*16;
        uu[ct][j] = bf2f(u_bf[idx]); zz[ct][j] = bf2f(z_bf[idx]); gg[ct][j] = bf2f(g_bf[idx]);
      }
    }
  }
  __syncthreads();

  const int ar = ln & 15, ag = (ln >> 4)*8;
  for (int step = 0; step < 4096; ++step) {
    // ---- matvec: A = HQ rows (batches 0-3 + zeros), B = W fragments ----
    const signed char* hq = &HQ[step & 1][ar][ag];
    i32x4 a0 = {0,0,0,0}, a1 = a0, a2 = a0, a3 = a0;
    #pragma unroll
    for (int kt = 0; kt < 32; ++kt) {
      long long av = *(const long long*)(hq + kt*32);
      a0 = __builtin_amdgcn_mfma_i32_16x16x32_i8(av, wfrag[kt*4+0], a0, 0, 0, 0);
      a1 = __builtin_amdgcn_mfma_i32_16x16x32_i8(av, wfrag[kt*4+1], a1, 0, 0, 0);
      a2 = __builtin_amdgcn_mfma_i32_16x16x32_i8(av, wfrag[kt*4+2], a2, 0, 0, 0);
      a3 = __builtin_amdgcn_mfma_i32_16x16x32_i8(av, wfrag[kt*4+3], a3, 0, 0, 0);
    }
    float nm[4] = {0.f, 0.f, 0.f, 0.f};
    if (epi) {
      i32x4 acc[4] = {a0, a1, a2, a3};
      #pragma unroll
      for (int ct = 0; ct < 4; ++ct) {
        #pragma unroll
        for (int j = 0; j < 4; ++j) {
          float y = (float)acc[ct][j]*(sWr[ct]*shc[j]) + uu[ct][j];
          float gate = fsigmoid(y);
          float h0 = hst[ct][j];
          float hn = h0 + gate*(zz[ct][j] - h0) + gg[ct][j]*h0;
          hst[ct][j] = hn;
          nm[j] = fmaxf(nm[j], fabsf(hn));
          h_seq[((size_t)(j*4096 + step))*1024 + colb + ct*16] = f2bf(hn);
        }
      }
      #pragma unroll
      for (int m = 1; m < 16; m <<= 1) {
        nm[0] = fmaxf(nm[0], __shfl_xor(nm[0], m));
        nm[1] = fmaxf(nm[1], __shfl_xor(nm[1], m));
        nm[2] = fmaxf(nm[2], __shfl_xor(nm[2], m));
        nm[3] = fmaxf(nm[3], __shfl_xor(nm[3], m));
      }
      if (ln == 0) *(float4*)&smax[w][0] = make_float4(nm[0], nm[1], nm[2], nm[3]);
    }
    __syncthreads();
    if (epi) {
      float g0 = 1e-20f, g1 = 1e-20f, g2 = 1e-20f, g3 = 1e-20f;
      #pragma unroll
      for (int w2 = 0; w2 < 16; ++w2) {
        g0 = fmaxf(g0, smax[w2][0]); g1 = fmaxf(g1, smax[w2][1]);
        g2 = fmaxf(g2, smax[w2][2]); g3 = fmaxf(g3, smax[w2][3]);
      }
      float inv0 = 127.f/g0, inv1 = 127.f/g1, inv2 = 127.f/g2, inv3 = 127.f/g3;
      shc[0] = g0*(1.f/127.f); shc[1] = g1*(1.f/127.f);
      shc[2] = g2*(1.f/127.f); shc[3] = g3*(1.f/127.f);
      float invs[4] = {inv0, inv1, inv2, inv3};
      #pragma unroll
      for (int ct = 0; ct < 4; ++ct) {
        #pragma unroll
        for (int j = 0; j < 4; ++j) {
          int q = __float2int_rn(hst[ct][j]*invs[j]);
          HQ[(step+1) & 1][j][colb + ct*16] = (signed char)q;
        }
      }
      int sn = (step+1 < 4096) ? step+1 : 4095;
      #pragma unroll
      for (int ct = 0; ct < 4; ++ct) {
        #pragma unroll
        for (int j = 0; j < 4; ++j) {
          size_t idx = ((size_t)(j*4096 + sn))*1024 + colb + ct*16;
          uu[ct][j] = bf2f(u_bf[idx]); zz[ct][j] = bf2f(z_bf[idx]); gg[ct][j] = bf2f(g_bf[idx]);
        }
      }
    }
    __syncthreads();
  }
}

// =======================================================================================
extern "C" void kernel_launch(void* const* d_in, const int* in_sizes, int n_in,
                              void* d_out, int out_size, void* d_ws, size_t ws_size,
                              hipStream_t stream)
{
  const float* x    = (const float*)d_in[0];
  const float* memk = (const float*)d_in[1];
  const float* memv = (const float*)d_in[2];
  const float* n1s  = (const float*)d_in[3];
  const float* n2s  = (const float*)d_in[4];
  const float* Wq = (const float*)d_in[5];   const float* bq = (const float*)d_in[6];
  const float* Wk = (const float*)d_in[7];   const float* bk = (const float*)d_in[8];
  const float* Wv = (const float*)d_in[9];   const float* bv = (const float*)d_in[10];
  const float* Wz = (const float*)d_in[11];  const float* bz = (const float*)d_in[12];
  const float* Wgz = (const float*)d_in[13]; const float* bgz = (const float*)d_in[14];
  const float* Wgh = (const float*)d_in[15]; const float* bgh = (const float*)d_in[16];
  const float* Wg1 = (const float*)d_in[17]; const float* bg1 = (const float*)d_in[18];
  const float* Wg2 = (const float*)d_in[19]; const float* bg2 = (const float*)d_in[20];
  const float* Wgc1 = (const float*)d_in[21]; const float* bgc1 = (const float*)d_in[22];
  const float* Wgc2 = (const float*)d_in[23]; const float* bgc2 = (const float*)d_in[24];
  const float* Awq = (const float*)d_in[25]; const float* abq = (const float*)d_in[26];
  const float* Awk = (const float*)d_in[27]; const float* abk = (const float*)d_in[28];
  const float* Awv = (const float*)d_in[29]; const float* abv = (const float*)d_in[30];
  const float* Awo = (const float*)d_in[31]; const float* abo = (const float*)d_in[32];
  const float* Wf1 = (const float*)d_in[33]; const float* bf1 = (const float*)d_in[34];
  const float* Wf2 = (const float*)d_in[35]; const float* bf2 = (const float*)d_in[36];
  (void)in_sizes; (void)n_in; (void)out_size; (void)ws_size;

  char* ws = (char*)d_ws;
  constexpr size_t MB = 1ull<<20;
  // persistent bf16 weights [0,32MB)
  ushort* WvT     = (ushort*)(ws + 0*MB);
  ushort* WzT     = (ushort*)(ws + 2*MB);
  ushort* WgzT    = (ushort*)(ws + 4*MB);
  ushort* WqAwqT  = (ushort*)(ws + 6*MB);
  ushort* AwkT    = (ushort*)(ws + 8*MB);
  ushort* AwvT    = (ushort*)(ws + 10*MB);
  ushort* AwoT    = (ushort*)(ws + 12*MB);
  ushort* Wf1T    = (ushort*)(ws + 14*MB);            // [4096][1024]
  ushort* Wf2Tc   = (ushort*)(ws + 22*MB);            // 4 chunks of [1024][1024]
  ushort* Wg1T    = (ushort*)(ws + 30*MB);
  ushort* Wg2T    = (ushort*)(ws + 30*MB + 512*1024);
  ushort* Wgc2T   = (ushort*)(ws + 31*MB);
  ushort* WkWgc1T = (ushort*)(ws + 31*MB + 512*1024);
  char*   WqT8    = ws + 30*MB;          // i8 Wgh^T (1MB) — overwrites Wg1T/Wg2T (dead)
  // small [32MB,33MB)
  float* bsum = (float*)(ws + 32*MB);
  float* bqh  = (float*)(ws + 32*MB + 4096);
  float* bkg  = (float*)(ws + 32*MB + 8192);
  float* sWp  = (float*)(ws + 32*MB + 16384);         // 4KB per-col scales
  // 32MB activation slots
  ushort* Abuf = (ushort*)(ws + 33*MB);   // xn -> gamma -> xn2
  ushort* Bbuf = (ushort*)(ws + 65*MB);   // z
  ushort* Cbuf = (ushort*)(ws + 97*MB);   // v -> h_seq
  ushort* Dbuf = (ushort*)(ws + 129*MB);  // qh -> att -> f1 chunk
  ushort* Ebuf = (ushort*)(ws + 161*MB);  // u
  // scratch inside d_out (64MB), all dead before the Awo epilogue writes d_out
  char* db = (char*)d_out;
  ushort* t1B   = (ushort*)(db + 0);        // 8MB
  ushort* memkB = (ushort*)(db + 8*MB);
  ushort* memvB = (ushort*)(db + 12*MB);
  ushort* khB   = (ushort*)(db + 16*MB);
  ushort* vhTB  = (ushort*)(db + 20*MB);
  ushort* gbB   = (ushort*)(db + 24*MB);    // 32MB
  ushort* WtmpB = (ushort*)(db + 56*MB);    // 2MB fusion A
  ushort* BtTB  = (ushort*)(db + 58*MB);    // 2MB fusion Bt

  const int M1 = 16384;
  dim3 b256(256);
  auto T = [&](const float* s, ushort* d, int K, int N){
    transpose_cvt<<<dim3(N/64, K/64), b256, 0, stream>>>(s, d, K, N);
  };
  #define G(EPI, Ap, Bp, bi, Cp, a0, a1, Mv, Nv, Kv) \
    gemm_bf16<EPI><<<dim3((Nv)/128,(Mv)/128), b256, 0, stream>>>( \
      (const ushort*)(Ap), (const ushort*)(Bp), bi, (void*)(Cp), a0, a1, Mv, Nv, Kv)

  // ---- fused weights (temps in d_out scratch) ----
  cvt_bf16<<<1024, b256, 0, stream>>>(Wq, WtmpB, 1048576);
  T(Awq, BtTB, 1024, 1024);
  G(7, WtmpB, BtTB, nullptr, WqAwqT, nullptr, nullptr, 1024, 1024, 1024);
  fuse_bias<<<4, b256, 0, stream>>>(bq, Awq, abq, bqh, 1024, 1024);
  cvt_bf16<<<1024, b256, 0, stream>>>(Wk, WtmpB, 1048576);
  T(Wgc1, BtTB, 1024, 256);
  G(7, WtmpB, BtTB, nullptr, WkWgc1T, nullptr, nullptr, 1024, 256, 1024);
  fuse_bias<<<1, b256, 0, stream>>>(bk, Wgc1, bgc1, bkg, 1024, 256);
  // ---- plain transposed weights ----
  T(Wv,WvT,1024,1024); T(Wz,WzT,1024,1024); T(Wgz,WgzT,1024,1024);
  T(Wg1,Wg1T,1024,256); T(Wg2,Wg2T,256,1024); T(Wgc2,Wgc2T,256,1024);
  T(Awk,AwkT,1024,1024); T(Awv,AwvT,1024,1024); T(Awo,AwoT,1024,1024);
  T(Wf1,Wf1T,1024,4096);
  for (int cch = 0; cch < 4; ++cch)
    T(Wf2 + (size_t)cch*1048576, Wf2Tc + (size_t)cch*1048576, 1024, 1024);
  bias_sum_k<<<4, b256, 0, stream>>>(bgz, bgh, bsum);
  cvt_bf16<<<2048, b256, 0, stream>>>(memk, memkB, 2097152);
  cvt_bf16<<<2048, b256, 0, stream>>>(memv, memvB, 2097152);

  // ---- forward ----
  rms_kernel<<<M1, b256, 0, stream>>>(x, n1s, Abuf);                    // xn
  G(0, Abuf, WzT, bz, Bbuf, nullptr, nullptr, M1, 1024, 1024);          // z
  G(0, Abuf, WvT, bv, Cbuf, nullptr, nullptr, M1, 1024, 1024);          // v
  G(0, Abuf, WqAwqT, bqh, Dbuf, nullptr, nullptr, M1, 1024, 1024);      // qh (fused)
  G(0, Bbuf, WgzT, bsum, Ebuf, nullptr, nullptr, M1, 1024, 1024);       // u
  G(1, Bbuf, Wg1T, bg1, t1B, nullptr, nullptr, M1, 256, 1024);          // t1z
  G(2, t1B, Wg2T, bg2, gbB, nullptr, nullptr, M1, 1024, 256);           // gamma_base
  G(1, Abuf, WkWgc1T, bkg, t1B, nullptr, nullptr, M1, 256, 1024);       // t1k (fused)
  G(3, t1B, Wgc2T, bgc2, Abuf, gbB, nullptr, M1, 1024, 256);            // gamma -> A
  quant_w<<<64, b256, 0, stream>>>(Wgh, WqT8, sWp);                     // i8 Wgh^T + scales
  G(0, memkB, AwkT, abk, khB, nullptr, nullptr, 2048, 1024, 1024);      // kh
  G(6, memvB, AwvT, abv, vhTB, nullptr, nullptr, 2048, 1024, 1024);     // vhT
  attn_kernel<<<dim3(64,8,4), b256, 0, stream>>>(Dbuf, khB, vhTB, Dbuf); // att in-place
  G(4, Dbuf, AwoT, abo, d_out, (const void*)x, (const void*)Cbuf, M1, 1024, 1024); // x+mem+0.1v
  scan_kernel<<<1, dim3(1024), 0, stream>>>((const char*)WqT8, sWp,
                                            Ebuf, Bbuf, Abuf, Cbuf);    // h_seq -> Cbuf
  addrms2_kernel<<<M1, b256, 0, stream>>>((float*)d_out, Cbuf, n2s, Abuf); // merge + norm2
  for (int cch = 0; cch < 4; ++cch) {
    G(1, Abuf, Wf1T + (size_t)cch*1048576, bf1 + cch*1024, Dbuf, nullptr, nullptr, M1, 1024, 1024);
    G(5, Dbuf, Wf2Tc + (size_t)cch*1048576, (cch==0 ? bf2 : nullptr), d_out, nullptr, nullptr, M1, 1024, 1024);
  }
  #undef G
}

// Round 12
// 12038.828 us; speedup vs baseline: 11.2258x; 11.2258x over previous
//
#include <hip/hip_runtime.h>
#include <stdint.h>

typedef short s16x8 __attribute__((ext_vector_type(8)));
typedef float f32x4 __attribute__((ext_vector_type(4)));
typedef uint  u32x4 __attribute__((ext_vector_type(4)));

#define DEV static __device__ __forceinline__

DEV float bf2f(ushort u){ union{uint i;float f;}v; v.i=((uint)u)<<16; return v.f; }
DEV ushort f2bf(float f){ union{float f;uint i;}v; v.f=f; return (ushort)((v.i + 0x7FFFu + ((v.i>>16)&1u))>>16); }
DEV float fsigmoid(float x){ return 1.f/(1.f+__expf(-x)); }
DEV float fgelu(float x){
  float u = 0.7978845608028654f*(x + 0.044715f*x*x*x);
  float e = __expf(2.f*u);
  float th = 1.f - 2.f/(e+1.f);   // tanh(u), stable
  return 0.5f*x*(1.f+th);
}
DEV f32x4 mfma16(s16x8 a, s16x8 b, f32x4 c){
  return __builtin_amdgcn_mfma_f32_16x16x32_bf16(a,b,c,0,0,0);
}

// coherent (L1+L2-bypass) 64-bit store to the device coherence point
DEV void store_u64_coherent(unsigned long long* p, unsigned long long v){
  asm volatile("global_store_dwordx2 %0, %1, off sc0 sc1" :: "v"(p), "v"(v) : "memory");
}
// coherent batched load of 8 consecutive u64 words (4 x dwordx4), self-waiting
DEV void load8_u64_coherent(const unsigned long long* p, u32x4& r0, u32x4& r1,
                            u32x4& r2, u32x4& r3){
  asm volatile("global_load_dwordx4 %0, %4, off sc0 sc1\n\t"
               "global_load_dwordx4 %1, %4, off offset:16 sc0 sc1\n\t"
               "global_load_dwordx4 %2, %4, off offset:32 sc0 sc1\n\t"
               "global_load_dwordx4 %3, %4, off offset:48 sc0 sc1\n\t"
               "s_waitcnt vmcnt(0)"
               : "=&v"(r0), "=&v"(r1), "=&v"(r2), "=&v"(r3)
               : "v"(p) : "memory");
}

// ---------------- transpose + f32->bf16 convert: dst[N][K] = bf16(src[K][N]) ----------------
__global__ __launch_bounds__(256) void transpose_cvt(const float* __restrict__ src,
                                                     ushort* __restrict__ dst, int K, int N){
  __shared__ float tile[64][65];
  int tk = blockIdx.y*64, tn = blockIdx.x*64;
  int t = threadIdx.x;
  int c4 = (t & 15)*4, r0 = t >> 4;
  #pragma unroll
  for (int p=0;p<4;++p){
    int r = r0 + p*16;
    float4 v = *(const float4*)(src + (size_t)(tk+r)*N + tn + c4);
    tile[r][c4+0]=v.x; tile[r][c4+1]=v.y; tile[r][c4+2]=v.z; tile[r][c4+3]=v.w;
  }
  __syncthreads();
  #pragma unroll
  for (int p=0;p<4;++p){
    int n = r0 + p*16;
    ushort4 o = make_ushort4(f2bf(tile[c4+0][n]), f2bf(tile[c4+1][n]),
                             f2bf(tile[c4+2][n]), f2bf(tile[c4+3][n]));
    *(ushort4*)(dst + (size_t)(tn+n)*K + tk + c4) = o;
  }
}

// ---------------- elementwise f32->bf16 ----------------
__global__ __launch_bounds__(256) void cvt_bf16(const float* __restrict__ s,
                                                ushort* __restrict__ d, int n){
  int i = (blockIdx.x*256 + threadIdx.x)*4;
  if (i < n){
    float4 v = *(const float4*)(s + i);
    ushort4 o = make_ushort4(f2bf(v.x), f2bf(v.y), f2bf(v.z), f2bf(v.w));
    *(ushort4*)(d + i) = o;
  }
}

__global__ __launch_bounds__(256) void bias_sum_k(const float* __restrict__ a,
                                                  const float* __restrict__ b,
                                                  float* __restrict__ o){
  int i = blockIdx.x*256 + threadIdx.x;
  if (i < 1024) o[i] = a[i] + b[i];
}

// fused bias: o[n] = sum_k b_in[k]*W[k][n] + b_out[n]
__global__ __launch_bounds__(256) void fuse_bias(const float* __restrict__ b_in,
                                                 const float* __restrict__ W,
                                                 const float* __restrict__ b_out,
                                                 float* __restrict__ o, int K, int N){
  int n = blockIdx.x*256 + threadIdx.x;
  if (n < N){
    float s = b_out[n];
    for (int k=0;k<K;++k) s += b_in[k]*W[(size_t)k*N + n];
    o[n] = s;
  }
}

// ---------------- RMSNorm: f32 in -> bf16 out (does not modify input) ----------------
__global__ __launch_bounds__(256) void rms_kernel(const float* __restrict__ x,
                                                  const float* __restrict__ scale,
                                                  ushort* __restrict__ out){
  int row = blockIdx.x, t = threadIdx.x;
  const float* xr = x + (size_t)row*1024;
  float4 v = *(const float4*)(xr + t*4);
  float ss = v.x*v.x + v.y*v.y + v.z*v.z + v.w*v.w;
  #pragma unroll
  for (int o=1;o<64;o<<=1) ss += __shfl_xor(ss, o);
  __shared__ float wsum[4];
  if ((t & 63)==0) wsum[t>>6] = ss;
  __syncthreads();
  float tot = wsum[0]+wsum[1]+wsum[2]+wsum[3];
  float rstd = rsqrtf(tot*(1.f/1024.f) + 1e-6f);
  float4 sc = *(const float4*)(scale + t*4);
  ushort4 o4 = make_ushort4(f2bf(v.x*sc.x*rstd), f2bf(v.y*sc.y*rstd),
                            f2bf(v.z*sc.z*rstd), f2bf(v.w*sc.w*rstd));
  *(ushort4*)(out + (size_t)row*1024 + t*4) = o4;
}

// ---------------- GEMM: C = epi(A[M][K](bf16) @ Bt[N][K](bf16)^T + bias) ----------------
// Staging via global_load_lds (16B/lane, linear-in-lane LDS layout — m97 pattern).
// EPI: 0 bf16  1 gelu->bf16  2 sigmoid->bf16  3 clip(sigmoid*aux0)->bf16
//      4 f32 = v + aux0_f32 + 0.1*aux1_bf16   5 f32 +=   6 bf16 scattered vhT
//      7 bf16 transposed store [col*M+row]
template<int EPI>
__global__ __launch_bounds__(256,2) void gemm_bf16(
    const ushort* __restrict__ A, const ushort* __restrict__ Bt,
    const float* __restrict__ bias, void* __restrict__ Cout,
    const void* __restrict__ aux0, const void* __restrict__ aux1,
    int M, int N, int K)
{
  __shared__ ushort Al[128*32];
  __shared__ ushort Bl[128*32];
  const int t = threadIdx.x, ln = t & 63;
  const int m0 = blockIdx.y*128, n0 = blockIdx.x*128;
  const int wv = t >> 6, wr = wv >> 1, wc = wv & 1;
  const int lr = ln & 15, lk = ln >> 4;
  f32x4 acc[4][4] = {};
  for (int kk = 0; kk < K; kk += 32) {
    #pragma unroll
    for (int cc = 0; cc < 2; ++cc) {
      int e = cc*256 + t;
      int r = e >> 2, sg = e & 3;
      __builtin_amdgcn_global_load_lds((const uint*)(A  + (size_t)(m0+r)*K + kk + sg*8),
                                       (uint*)&Al[e*8], 16, 0, 0);
      __builtin_amdgcn_global_load_lds((const uint*)(Bt + (size_t)(n0+r)*K + kk + sg*8),
                                       (uint*)&Bl[e*8], 16, 0, 0);
    }
    __syncthreads();
    s16x8 af[4], bfr[4];
    #pragma unroll
    for (int m=0;m<4;++m) af[m]  = *(const s16x8*)&Al[(wr*64 + m*16 + lr)*32 + lk*8];
    #pragma unroll
    for (int n=0;n<4;++n) bfr[n] = *(const s16x8*)&Bl[(wc*64 + n*16 + lr)*32 + lk*8];
    #pragma unroll
    for (int m=0;m<4;++m)
      #pragma unroll
      for (int n=0;n<4;++n)
        acc[m][n] = mfma16(af[m], bfr[n], acc[m][n]);
    __syncthreads();
  }
  #pragma unroll
  for (int m=0;m<4;++m){
    #pragma unroll
    for (int n=0;n<4;++n){
      #pragma unroll
      for (int j=0;j<4;++j){
        int row = m0 + wr*64 + m*16 + lk*4 + j;
        int col = n0 + wc*64 + n*16 + lr;
        float v = acc[m][n][j] + (bias ? bias[col] : 0.f);
        size_t idx = (size_t)row*N + col;
        if constexpr (EPI==0){ ((ushort*)Cout)[idx] = f2bf(v); }
        else if constexpr (EPI==1){ ((ushort*)Cout)[idx] = f2bf(fgelu(v)); }
        else if constexpr (EPI==2){ ((ushort*)Cout)[idx] = f2bf(fsigmoid(v)); }
        else if constexpr (EPI==3){
          float g = fsigmoid(v) * bf2f(((const ushort*)aux0)[idx]);
          g = fminf(fmaxf(g, 1e-6f), 1.f-1e-6f);
          ((ushort*)Cout)[idx] = f2bf(g);
        }
        else if constexpr (EPI==4){
          float o = v + ((const float*)aux0)[idx] + 0.1f*bf2f(((const ushort*)aux1)[idx]);
          ((float*)Cout)[idx] = o;
        }
        else if constexpr (EPI==5){ ((float*)Cout)[idx] += v; }
        else if constexpr (EPI==6){
          int bb = row >> 9, mm = row & 511, hh = col >> 7, dd = col & 127;
          ((ushort*)Cout)[ (((size_t)(bb*8 + hh)*128 + dd) << 9) + mm ] = f2bf(v);
        }
        else if constexpr (EPI==7){
          ((ushort*)Cout)[(size_t)col*M + row] = f2bf(v);
        }
      }
    }
  }
}

// ---------------- memory attention: per (b,h,s-tile 64), M=512, hd=128 -------------------
__global__ __launch_bounds__(256,1) void attn_kernel(
  const ushort* __restrict__ qh, const ushort* __restrict__ kh,
  const ushort* __restrict__ vhT, ushort* __restrict__ att)
{
  __shared__ ushort P[4*16*512];   // 64KB, per-wave 16x512 bf16, XOR-swizzled
  const int t = threadIdx.x, ln = t & 63, wv = t >> 6;
  const int lr = ln & 15, lk = ln >> 4;
  const int b = blockIdx.z, h = blockIdx.y, s0 = blockIdx.x*64;

  const ushort* qrow = qh + (size_t)(b*4096 + s0 + wv*16 + lr)*1024 + h*128 + lk*8;
  s16x8 qf[4];
  #pragma unroll
  for (int kt=0;kt<4;++kt) qf[kt] = *(const s16x8*)(qrow + kt*32);
  __syncthreads();   // all q reads complete before any in-place writes later

  f32x4 zero4 = {0.f,0.f,0.f,0.f};
  f32x4 sacc[32];
  #pragma unroll
  for (int i=0;i<32;++i) sacc[i] = zero4;

  const ushort* kbase = kh + (size_t)(b*512)*1024 + h*128 + lk*8;
  #pragma unroll
  for (int mt=0;mt<32;++mt){
    const ushort* krow = kbase + (size_t)(mt*16 + lr)*1024;
    #pragma unroll
    for (int kt=0;kt<4;++kt){
      s16x8 kf = *(const s16x8*)(krow + kt*32);
      sacc[mt] = mfma16(qf[kt], kf, sacc[mt]);
    }
  }
  const float scale = 0.08838834764831845f;  // 1/sqrt(128)
  float inv[4];
  #pragma unroll
  for (int j=0;j<4;++j){
    float m = -3.4e38f;
    #pragma unroll
    for (int mt=0;mt<32;++mt) m = fmaxf(m, sacc[mt][j]);
    m = fmaxf(m, __shfl_xor(m,1)); m = fmaxf(m, __shfl_xor(m,2));
    m = fmaxf(m, __shfl_xor(m,4)); m = fmaxf(m, __shfl_xor(m,8));
    float s = 0.f;
    #pragma unroll
    for (int mt=0;mt<32;++mt){
      float p = __expf((sacc[mt][j]-m)*scale);
      sacc[mt][j] = p; s += p;
    }
    s += __shfl_xor(s,1); s += __shfl_xor(s,2);
    s += __shfl_xor(s,4); s += __shfl_xor(s,8);
    inv[j] = 1.f/s;
  }
  char* pb = (char*)P + wv*16384;
  #pragma unroll
  for (int j=0;j<4;++j){
    int row = lk*4 + j;
    uint xr = (uint)((row & 7) << 4);
    #pragma unroll
    for (int mt=0;mt<32;++mt){
      int col = mt*16 + lr;
      *(ushort*)(pb + row*1024 + (((uint)(col*2)) ^ xr)) = f2bf(sacc[mt][j]);
    }
  }
  f32x4 oacc[8];
  #pragma unroll
  for (int i=0;i<8;++i) oacc[i] = zero4;
  const ushort* vb = vhT + (size_t)(b*8 + h)*128*512;
  const char* prow = (char*)P + wv*16384 + lr*1024;
  uint xrr = (uint)((lr & 7) << 4);
  #pragma unroll
  for (int km=0;km<16;++km){
    s16x8 pf = *(const s16x8*)(prow + (((uint)((km*32 + lk*8)*2)) ^ xrr));
    #pragma unroll
    for (int dt=0;dt<8;++dt){
      s16x8 vf = *(const s16x8*)(vb + (size_t)(dt*16 + lr)*512 + km*32 + lk*8);
      oacc[dt] = mfma16(pf, vf, oacc[dt]);
    }
  }
  ushort* ob = att + (size_t)(b*4096 + s0 + wv*16)*1024 + h*128;
  #pragma unroll
  for (int dt=0;dt<8;++dt){
    #pragma unroll
    for (int j=0;j<4;++j){
      int row = lk*4 + j, col = dt*16 + lr;
      ob[(size_t)row*1024 + col] = f2bf(oacc[dt][j]*inv[j]);
    }
  }
}

// ---------------- sequential gated scan: 64 blocks x 16 cols, MFMA matvec ----------------
// Cross-block sync: TAGGED DATA through the device coherence point (sc0 sc1 on both the
// producer store and the consumer polling loads). Word = (step_tag<<32) | bf16x2 payload.
#define SCAN_NB 64
__global__ __launch_bounds__(256,1) void scan_kernel(
  const float* __restrict__ Wgh,
  const ushort* __restrict__ u_bf, const ushort* __restrict__ z_bf,
  const ushort* __restrict__ g_bf, float* __restrict__ xres,
  unsigned long long* __restrict__ h_buf)
{
  __shared__ ushort WL[16*1032];   // W^T bf16 [c][k], stride 1032
  __shared__ ushort HL[5*1032];    // rows 0..3 = h batches (bf16), row 4 = zeros
  __shared__ float  red[4][16][4]; // [wave][c][b]
  const int t = threadIdx.x, blk = blockIdx.x;
  const int ln = t & 63, wv = t >> 6;

  // ---- load W slice (coalesced 64B groups), transpose to LDS bf16 ----
  {
    const int c = t & 15, i0q = (t >> 4) * 64;
    for (int j = 0; j < 64; ++j) {
      int i = i0q + j;
      WL[c*1032 + i] = f2bf(Wgh[(size_t)i*1024 + blk*16 + c]);
    }
  }
  for (int e = t; e < 1032; e += 256) HL[4*1032 + e] = 0;  // zero row

  float hmine = 0.f;
  const int c_ep = t & 15, b_ep = t >> 4;   // valid t<64
  float uu=0.f, zz=0.f, gg=0.f, xv=0.f;
  if (t < 64) {
    size_t i0 = ((size_t)(b_ep*4096))*1024 + blk*16 + c_ep;
    uu = bf2f(u_bf[i0]); zz = bf2f(z_bf[i0]); gg = bf2f(g_bf[i0]); xv = xres[i0];
  }
  __syncthreads();

  // fragment bases: A row = ln&15 (rows>=4 alias zero row), k-chunk = ln>>4
  const int arow = ln & 15, akc = ln >> 4;
  const ushort* Abase = &HL[(arow < 4 ? arow : 4)*1032 + akc*8];
  const ushort* Bbase = &WL[(ln & 15)*1032 + akc*8];
  // consumer mapping: thread t handles words [t*8, t*8+8) = batch t>>6, k [(t&63)*16,+16)
  const int hb_t = t >> 6, hk0 = (t & 63)*16;

  for (int step = 0; step < 4096; ++step) {
    // ---- poll tagged h words through the coherence point ----
    {
      const unsigned long long* hs = h_buf + (size_t)(step & 1)*2048 + t*8;
      u32x4 r0, r1, r2, r3;
      while (true) {
        load8_u64_coherent(hs, r0, r1, r2, r3);
        uint st = (uint)step;
        if (r0.y==st && r0.w==st && r1.y==st && r1.w==st &&
            r2.y==st && r2.w==st && r3.y==st && r3.w==st) break;
      }
      uint* dst = (uint*)&HL[hb_t*1032 + hk0];
      *(uint4*)(dst + 0) = make_uint4(r0.x, r0.z, r1.x, r1.z);
      *(uint4*)(dst + 4) = make_uint4(r2.x, r2.z, r3.x, r3.z);
    }
    __syncthreads();
    // ---- MFMA partial: wave wv covers K in [wv*256, wv*256+256) ----
    f32x4 acc = {0.f,0.f,0.f,0.f};
    #pragma unroll
    for (int m = 0; m < 8; ++m) {
      int koff = wv*256 + m*32;
      s16x8 a = *(const s16x8*)(Abase + koff);
      s16x8 b = *(const s16x8*)(Bbase + koff);
      acc = mfma16(a, b, acc);
    }
    if (ln < 16) *(f32x4*)&red[wv][ln][0] = acc;   // lane=col, regs=rows 0..3
    __syncthreads();
    // ---- epilogue (wave 0) ----
    if (t < 64) {
      float y = red[0][c_ep][b_ep] + red[1][c_ep][b_ep]
              + red[2][c_ep][b_ep] + red[3][c_ep][b_ep];
      float gate = fsigmoid(y + uu);
      float hn = hmine + gate*(zz - hmine) + gg*hmine;
      hmine = hn;
      int colg = blk*16 + c_ep;
      float hup = __shfl_down(hn, 1);
      if ((t & 1) == 0) {     // pack (even,odd) cols + tag, single coherent 64-bit store
        unsigned long long pk = ((unsigned long long)(uint)(step+1) << 32)
                              | ((uint)f2bf(hup) << 16) | (uint)f2bf(hn);
        store_u64_coherent(h_buf + (size_t)((step+1)&1)*2048 + b_ep*512 + (colg>>1), pk);
      }
      size_t idx = ((size_t)(b_ep*4096 + step))*1024 + colg;
      xres[idx] = xv + hn;
      int sn = (step+1 < 4096) ? step+1 : 4095;
      size_t idxn = ((size_t)(b_ep*4096 + sn))*1024 + colg;
      uu = bf2f(u_bf[idxn]); zz = bf2f(z_bf[idxn]); gg = bf2f(g_bf[idxn]);
      xv = xres[idxn];
    }
  }
}

// =======================================================================================
extern "C" void kernel_launch(void* const* d_in, const int* in_sizes, int n_in,
                              void* d_out, int out_size, void* d_ws, size_t ws_size,
                              hipStream_t stream)
{
  const float* x    = (const float*)d_in[0];
  const float* memk = (const float*)d_in[1];
  const float* memv = (const float*)d_in[2];
  const float* n1s  = (const float*)d_in[3];
  const float* n2s  = (const float*)d_in[4];
  const float* Wq = (const float*)d_in[5];   const float* bq = (const float*)d_in[6];
  const float* Wk = (const float*)d_in[7];   const float* bk = (const float*)d_in[8];
  const float* Wv = (const float*)d_in[9];   const float* bv = (const float*)d_in[10];
  const float* Wz = (const float*)d_in[11];  const float* bz = (const float*)d_in[12];
  const float* Wgz = (const float*)d_in[13]; const float* bgz = (const float*)d_in[14];
  const float* Wgh = (const float*)d_in[15]; const float* bgh = (const float*)d_in[16];
  const float* Wg1 = (const float*)d_in[17]; const float* bg1 = (const float*)d_in[18];
  const float* Wg2 = (const float*)d_in[19]; const float* bg2 = (const float*)d_in[20];
  const float* Wgc1 = (const float*)d_in[21]; const float* bgc1 = (const float*)d_in[22];
  const float* Wgc2 = (const float*)d_in[23]; const float* bgc2 = (const float*)d_in[24];
  const float* Awq = (const float*)d_in[25]; const float* abq = (const float*)d_in[26];
  const float* Awk = (const float*)d_in[27]; const float* abk = (const float*)d_in[28];
  const float* Awv = (const float*)d_in[29]; const float* abv = (const float*)d_in[30];
  const float* Awo = (const float*)d_in[31]; const float* abo = (const float*)d_in[32];
  const float* Wf1 = (const float*)d_in[33]; const float* bf1 = (const float*)d_in[34];
  const float* Wf2 = (const float*)d_in[35]; const float* bf2 = (const float*)d_in[36];
  (void)in_sizes; (void)n_in; (void)out_size; (void)ws_size;

  char* ws = (char*)d_ws;
  constexpr size_t MB = 1ull<<20;
  // persistent bf16 weights [0,32MB)
  ushort* WvT     = (ushort*)(ws + 0*MB);
  ushort* WzT     = (ushort*)(ws + 2*MB);
  ushort* WgzT    = (ushort*)(ws + 4*MB);
  ushort* WqAwqT  = (ushort*)(ws + 6*MB);
  ushort* AwkT    = (ushort*)(ws + 8*MB);
  ushort* AwvT    = (ushort*)(ws + 10*MB);
  ushort* AwoT    = (ushort*)(ws + 12*MB);
  ushort* Wf1T    = (ushort*)(ws + 14*MB);            // [4096][1024]
  ushort* Wf2Tc   = (ushort*)(ws + 22*MB);            // 4 chunks of [1024][1024]
  ushort* Wg1T    = (ushort*)(ws + 30*MB);
  ushort* Wg2T    = (ushort*)(ws + 30*MB + 512*1024);
  ushort* Wgc2T   = (ushort*)(ws + 31*MB);
  ushort* WkWgc1T = (ushort*)(ws + 31*MB + 512*1024);
  // small [32MB,33MB)
  float* bsum = (float*)(ws + 32*MB);
  float* bqh  = (float*)(ws + 32*MB + 4096);
  float* bkg  = (float*)(ws + 32*MB + 8192);
  char*  scanB = ws + 32*MB + 65536;                  // tagged h_buf: 2 x 2048 x 8B = 32KB
  // 32MB activation slots
  ushort* Abuf = (ushort*)(ws + 33*MB);   // xn -> gamma
  ushort* Bbuf = (ushort*)(ws + 65*MB);   // z
  ushort* Cbuf = (ushort*)(ws + 97*MB);   // v -> xn2
  ushort* Dbuf = (ushort*)(ws + 129*MB);  // qh -> att -> f1 chunk
  ushort* Ebuf = (ushort*)(ws + 161*MB);  // u
  // scratch inside d_out (64MB), all dead before the Awo epilogue writes d_out
  char* db = (char*)d_out;
  ushort* t1B   = (ushort*)(db + 0);        // 8MB
  ushort* memkB = (ushort*)(db + 8*MB);
  ushort* memvB = (ushort*)(db + 12*MB);
  ushort* khB   = (ushort*)(db + 16*MB);
  ushort* vhTB  = (ushort*)(db + 20*MB);
  ushort* gbB   = (ushort*)(db + 24*MB);    // 32MB
  ushort* WtmpB = (ushort*)(db + 56*MB);    // 2MB fusion A
  ushort* BtTB  = (ushort*)(db + 58*MB);    // 2MB fusion Bt

  const int M1 = 16384;
  dim3 b256(256);
  auto T = [&](const float* s, ushort* d, int K, int N){
    transpose_cvt<<<dim3(N/64, K/64), b256, 0, stream>>>(s, d, K, N);
  };
  #define G(EPI, Ap, Bp, bi, Cp, a0, a1, Mv, Nv, Kv) \
    gemm_bf16<EPI><<<dim3((Nv)/128,(Mv)/128), b256, 0, stream>>>( \
      (const ushort*)(Ap), (const ushort*)(Bp), bi, (void*)(Cp), a0, a1, Mv, Nv, Kv)

  // ---- fused weights (temps in d_out scratch) ----
  cvt_bf16<<<1024, b256, 0, stream>>>(Wq, WtmpB, 1048576);
  T(Awq, BtTB, 1024, 1024);
  G(7, WtmpB, BtTB, nullptr, WqAwqT, nullptr, nullptr, 1024, 1024, 1024);
  fuse_bias<<<4, b256, 0, stream>>>(bq, Awq, abq, bqh, 1024, 1024);
  cvt_bf16<<<1024, b256, 0, stream>>>(Wk, WtmpB, 1048576);
  T(Wgc1, BtTB, 1024, 256);
  G(7, WtmpB, BtTB, nullptr, WkWgc1T, nullptr, nullptr, 1024, 256, 1024);
  fuse_bias<<<1, b256, 0, stream>>>(bk, Wgc1, bgc1, bkg, 1024, 256);
  // ---- plain transposed weights ----
  T(Wv,WvT,1024,1024); T(Wz,WzT,1024,1024); T(Wgz,WgzT,1024,1024);
  T(Wg1,Wg1T,1024,256); T(Wg2,Wg2T,256,1024); T(Wgc2,Wgc2T,256,1024);
  T(Awk,AwkT,1024,1024); T(Awv,AwvT,1024,1024); T(Awo,AwoT,1024,1024);
  T(Wf1,Wf1T,1024,4096);
  for (int cch = 0; cch < 4; ++cch)
    T(Wf2 + (size_t)cch*1048576, Wf2Tc + (size_t)cch*1048576, 1024, 1024);
  bias_sum_k<<<4, b256, 0, stream>>>(bgz, bgh, bsum);
  cvt_bf16<<<2048, b256, 0, stream>>>(memk, memkB, 2097152);
  cvt_bf16<<<2048, b256, 0, stream>>>(memv, memvB, 2097152);

  // ---- forward ----
  rms_kernel<<<M1, b256, 0, stream>>>(x, n1s, Abuf);                    // xn
  G(0, Abuf, WzT, bz, Bbuf, nullptr, nullptr, M1, 1024, 1024);          // z
  G(0, Abuf, WvT, bv, Cbuf, nullptr, nullptr, M1, 1024, 1024);          // v
  G(0, Abuf, WqAwqT, bqh, Dbuf, nullptr, nullptr, M1, 1024, 1024);      // qh (fused)
  G(0, Bbuf, WgzT, bsum, Ebuf, nullptr, nullptr, M1, 1024, 1024);       // u
  G(1, Bbuf, Wg1T, bg1, t1B, nullptr, nullptr, M1, 256, 1024);          // t1z
  G(2, t1B, Wg2T, bg2, gbB, nullptr, nullptr, M1, 1024, 256);           // gamma_base
  G(1, Abuf, WkWgc1T, bkg, t1B, nullptr, nullptr, M1, 256, 1024);       // t1k (fused)
  G(3, t1B, Wgc2T, bgc2, Abuf, gbB, nullptr, M1, 1024, 256);            // gamma -> A
  G(0, memkB, AwkT, abk, khB, nullptr, nullptr, 2048, 1024, 1024);      // kh
  G(6, memvB, AwvT, abv, vhTB, nullptr, nullptr, 2048, 1024, 1024);     // vhT
  attn_kernel<<<dim3(64,8,4), b256, 0, stream>>>(Dbuf, khB, vhTB, Dbuf); // att in-place
  G(4, Dbuf, AwoT, abo, d_out, (const void*)x, (const void*)Cbuf, M1, 1024, 1024); // x+mem+0.1v
  hipMemsetAsync(scanB, 0, 32768, stream);
  scan_kernel<<<SCAN_NB, b256, 0, stream>>>(Wgh, Ebuf, Bbuf, Abuf, (float*)d_out,
                                            (unsigned long long*)scanB);
  rms_kernel<<<M1, b256, 0, stream>>>((const float*)d_out, n2s, Cbuf);  // xn2
  for (int cch = 0; cch < 4; ++cch) {
    G(1, Cbuf, Wf1T + (size_t)cch*1048576, bf1 + cch*1024, Dbuf, nullptr, nullptr, M1, 1024, 1024);
    G(5, Dbuf, Wf2Tc + (size_t)cch*1048576, (cch==0 ? bf2 : nullptr), d_out, nullptr, nullptr, M1, 1024, 1024);
  }
  #undef G
}